// Round 4
// baseline (417.327 us; speedup 1.0000x reference)
//
#include <hip/hip_runtime.h>
#include <hip/hip_bf16.h>
#include <cstdint>

// GraphSAGE 3-layer + edge predictor.
// Factoring: segsum(concat(h[src],e)@Wm.T+bm, dst) = g@Wmh.T + eagg@Wme.T + deg*bm
// Fused per-layer kernel: phase1 stage h/eagg/gather -> packed bf16 hi/lo LDS;
// phase2 msg MFMA -> nmean in LDS; phase3 apply MFMA -> fp32 h_next.
// hi/lo split (3 MFMA) keeps error ~2^-17. A and B packed with the SAME
// (lane,elem)->k map -> invariant to HW internal k ordering.

static inline int cdiv(int a, int b) { return (a + b - 1) / b; }

typedef __attribute__((ext_vector_type(8))) short bf16x8;
typedef __attribute__((ext_vector_type(4))) float f32x4;

__device__ __forceinline__ ushort f2bf(float x) {
  union { float f; unsigned u; } c; c.f = x;
  unsigned r = c.u + 0x7FFFu + ((c.u >> 16) & 1u);
  return (ushort)(r >> 16);
}
__device__ __forceinline__ float bf2f(unsigned h) {
  union { unsigned u; float f; } c; c.u = h << 16;
  return c.f;
}

__device__ __forceinline__ f32x4 mfma3(bf16x8 ah, bf16x8 al, bf16x8 bh, bf16x8 bl,
                                       f32x4 acc) {
  acc = __builtin_amdgcn_mfma_f32_16x16x32_bf16(ah, bh, acc, 0, 0, 0);
  acc = __builtin_amdgcn_mfma_f32_16x16x32_bf16(al, bh, acc, 0, 0, 0);
  acc = __builtin_amdgcn_mfma_f32_16x16x32_bf16(ah, bl, acc, 0, 0, 0);
  return acc;
}

// packed-A LDS: region layout [plane][kt][q][row32][8] bf16 (tile = 1024 ushort)
__device__ __forceinline__ void wpack4(ushort* lds, int base, int KT, int row,
                                       int k0, float4 v) {
  int idx0 = base + ((k0 >> 5) * 4 + ((k0 >> 3) & 3)) * 256 + row * 8 + (k0 & 7);
  int idx1 = idx0 + KT * 1024;
  ushort h0 = f2bf(v.x), h1 = f2bf(v.y), h2 = f2bf(v.z), h3 = f2bf(v.w);
  uint2 uh, ul;
  uh.x = (unsigned)h0 | ((unsigned)h1 << 16);
  uh.y = (unsigned)h2 | ((unsigned)h3 << 16);
  ushort l0 = f2bf(v.x - bf2f(h0)), l1 = f2bf(v.y - bf2f(h1));
  ushort l2 = f2bf(v.z - bf2f(h2)), l3 = f2bf(v.w - bf2f(h3));
  ul.x = (unsigned)l0 | ((unsigned)l1 << 16);
  ul.y = (unsigned)l2 | ((unsigned)l3 << 16);
  *reinterpret_cast<uint2*>(&lds[idx0]) = uh;
  *reinterpret_cast<uint2*>(&lds[idx1]) = ul;
}

__device__ __forceinline__ void wpack1(ushort* lds, int base, int KT, int row,
                                       int k, float v) {
  int idx0 = base + ((k >> 5) * 4 + ((k >> 3) & 3)) * 256 + row * 8 + (k & 7);
  ushort h = f2bf(v);
  lds[idx0] = h;
  lds[idx0 + KT * 1024] = f2bf(v - bf2f(h));
}

__device__ __forceinline__ bf16x8 rfrag(const ushort* lds, int base, int KT,
                                        int plane, int kt, int lane, int mh) {
  int idx = base + ((plane * KT + kt) * 4 + (lane >> 4)) * 256 +
            ((lane & 15) + 16 * mh) * 8;
  return *reinterpret_cast<const bf16x8*>(&lds[idx]);
}

// ---------------- CSR build ----------------
__global__ __launch_bounds__(256) void k_hist(const int* __restrict__ dst,
                                              int* __restrict__ cnt, int E) {
  int e = blockIdx.x * 256 + threadIdx.x;
  if (e < E) atomicAdd(&cnt[dst[e]], 1);
}

__global__ __launch_bounds__(1024) void k_scan(const int* __restrict__ cnt,
                                               int* __restrict__ offs, int n) {
  __shared__ int smem[1024];
  const int t = threadIdx.x;
  const int base = t * 10;
  int c[10];
  int s = 0;
#pragma unroll
  for (int i = 0; i < 10; ++i) {
    int idx = base + i;
    int v = (idx < n) ? cnt[idx] : 0;
    s += v;
    c[i] = s;
  }
  smem[t] = s;
  __syncthreads();
  for (int ofs = 1; ofs < 1024; ofs <<= 1) {
    int add = (t >= ofs) ? smem[t - ofs] : 0;
    __syncthreads();
    smem[t] += add;
    __syncthreads();
  }
  int excl = smem[t] - s;
  if (t == 0) offs[0] = 0;
#pragma unroll
  for (int i = 0; i < 10; ++i) {
    int idx = base + i;
    if (idx < n) offs[idx + 1] = excl + c[i];
  }
}

__global__ __launch_bounds__(256) void k_scatter(const int* __restrict__ src,
                                                 const int* __restrict__ dst,
                                                 const int* __restrict__ offs,
                                                 int* __restrict__ fill,
                                                 int* __restrict__ csr_edge,
                                                 int* __restrict__ csr_src, int E) {
  int e = blockIdx.x * 256 + threadIdx.x;
  if (e < E) {
    int d = dst[e];
    int pos = offs[d] + atomicAdd(&fill[d], 1);
    csr_edge[pos] = e;
    csr_src[pos] = src[e];
  }
}

// ---------------- weight prep (unchanged packing format) ----------------
struct WDesc {
  const float* W; ushort* hi; ushort* lo;
  int dout, KA, KApad, KB, Korig, NG16, KT, pred;
};
struct WDescs { WDesc d[7]; };

__global__ __launch_bounds__(256) void k_prep_W(WDescs P) {
  const WDesc d = P.d[blockIdx.y];
  int tid = blockIdx.x * 256 + threadIdx.x;
  if (tid >= d.KT * d.NG16 * 64) return;
  int lane = tid & 63;
  int g = (tid >> 6) % d.NG16;
  int t = (tid >> 6) / d.NG16;
  int col = g * 16 + (lane & 15);
  int kbase = t * 32 + ((lane >> 4) * 8);
  size_t o = (size_t)tid * 8;
#pragma unroll
  for (int j = 0; j < 8; ++j) {
    int kk = kbase + j;
    float w = 0.f;
    if (!d.pred) {
      if (col < d.dout) {
        if (kk < d.KApad) {
          if (kk < d.KA) w = d.W[(size_t)col * d.Korig + kk];
        } else {
          int kb = kk - d.KApad;
          if (kb < d.KB) w = d.W[(size_t)col * d.Korig + d.KA + kb];
        }
      }
    } else {
      if (col < 15) w = d.W[(size_t)col * 256 + kk];
      else if (col < 30) w = d.W[(size_t)(col - 15) * 256 + 128 + kk];
    }
    ushort h = f2bf(w);
    d.hi[o + j] = h;
    d.lo[o + j] = f2bf(w - bf2f(h));
  }
}

// ---------------- edge-feature aggregation (the big HBM read) ----------------
__global__ __launch_bounds__(64) void k_eagg(const float* __restrict__ efeats,
                                             const int* __restrict__ csr_edge,
                                             const int* __restrict__ offs,
                                             float* __restrict__ eagg,
                                             float* __restrict__ deg) {
  int d = blockIdx.x, lane = threadIdx.x;
  int s = offs[d], t = offs[d + 1];
  float2 acc = make_float2(0.f, 0.f), acc2 = make_float2(0.f, 0.f);
  int j = s;
  for (; j + 1 < t; j += 2) {
    int e0 = csr_edge[j], e1 = csr_edge[j + 1];
    float2 v0 = *reinterpret_cast<const float2*>(efeats + (size_t)e0 * 128 + lane * 2);
    float2 v1 = *reinterpret_cast<const float2*>(efeats + (size_t)e1 * 128 + lane * 2);
    acc.x += v0.x; acc.y += v0.y;
    acc2.x += v1.x; acc2.y += v1.y;
  }
  if (j < t) {
    int e0 = csr_edge[j];
    float2 v0 = *reinterpret_cast<const float2*>(efeats + (size_t)e0 * 128 + lane * 2);
    acc.x += v0.x; acc.y += v0.y;
  }
  acc.x += acc2.x; acc.y += acc2.y;
  *reinterpret_cast<float2*>(eagg + (size_t)d * 128 + lane * 2) = acc;
  if (lane == 0) deg[d] = (float)(t - s);
}

// ---------------- fused SAGE layer ----------------
// Block: 32 rows x full dout, NW waves. LDS regions G|H|E|NM, packed bf16 hi/lo.
template <int KTH, int KTNM, int NW, int HW, int DOUT>
__global__ __launch_bounds__(NW * 64) void k_layer(
    const float* __restrict__ hprev, const float* __restrict__ eagg,
    const float* __restrict__ deg, const int* __restrict__ csr_src,
    const int* __restrict__ offs,
    const ushort* __restrict__ Wmh, const ushort* __restrict__ Wml,
    const float* __restrict__ bm,
    const ushort* __restrict__ Wah, const ushort* __restrict__ Wal,
    const float* __restrict__ ba, float* __restrict__ hnext, int M) {
  constexpr int KTG = KTH;
  constexpr int KTE = 4;
  constexpr int NG16 = 2 * NW;
  constexpr int KTM = KTG + KTE;
  constexpr int KTA = KTH + KTNM;
  constexpr int BASE_G = 0;
  constexpr int BASE_H = 2 * KTG * 1024;
  constexpr int BASE_E = BASE_H + 2 * KTH * 1024;
  constexpr int BASE_NM = BASE_E + 2 * KTE * 1024;
  __shared__ ushort lds[BASE_NM + 2 * KTNM * 1024];

  const int tid = threadIdx.x;
  const int wid = tid >> 6, lane = tid & 63;
  const int row0 = blockIdx.x * 32;
  const int k0 = lane * 4;

  // ---- phase 1: stage hprev rows, eagg rows; gather-sum hprev[src] ----
  for (int r = wid; r < 32; r += NW) {
    const int gr = row0 + r;
    const bool ok = gr < M;
    if (lane < KTH * 8) {
      float4 v = make_float4(0.f, 0.f, 0.f, 0.f);
      if (ok && k0 < HW)
        v = *reinterpret_cast<const float4*>(hprev + (size_t)gr * HW + k0);
      wpack4(lds, BASE_H, KTH, r, k0, v);
    }
    if (lane < 32) {
      float4 v = make_float4(0.f, 0.f, 0.f, 0.f);
      if (ok) v = *reinterpret_cast<const float4*>(eagg + (size_t)gr * 128 + k0);
      wpack4(lds, BASE_E, KTE, r, k0, v);
    }
    if (lane < KTG * 8) {
      float4 acc = make_float4(0.f, 0.f, 0.f, 0.f);
      if (ok && k0 < HW) {
        int s = offs[gr], t = offs[gr + 1];
        int j = s;
        for (; j + 3 < t; j += 4) {
          int s0 = csr_src[j], s1 = csr_src[j + 1];
          int s2 = csr_src[j + 2], s3 = csr_src[j + 3];
          float4 v0 = *reinterpret_cast<const float4*>(hprev + (size_t)s0 * HW + k0);
          float4 v1 = *reinterpret_cast<const float4*>(hprev + (size_t)s1 * HW + k0);
          float4 v2 = *reinterpret_cast<const float4*>(hprev + (size_t)s2 * HW + k0);
          float4 v3 = *reinterpret_cast<const float4*>(hprev + (size_t)s3 * HW + k0);
          acc.x += (v0.x + v1.x) + (v2.x + v3.x);
          acc.y += (v0.y + v1.y) + (v2.y + v3.y);
          acc.z += (v0.z + v1.z) + (v2.z + v3.z);
          acc.w += (v0.w + v1.w) + (v2.w + v3.w);
        }
        for (; j < t; ++j) {
          int s0 = csr_src[j];
          float4 v0 = *reinterpret_cast<const float4*>(hprev + (size_t)s0 * HW + k0);
          acc.x += v0.x; acc.y += v0.y; acc.z += v0.z; acc.w += v0.w;
        }
      }
      wpack4(lds, BASE_G, KTG, r, k0, acc);
    }
  }
  __syncthreads();

  // ---- phase 2: msg GEMM (G|E) -> nmean packed into NM ----
  const int ng0 = wid * 2;
  const int colL = lane & 15;
  f32x4 acc00 = {0.f, 0.f, 0.f, 0.f}, acc01 = {0.f, 0.f, 0.f, 0.f};
  f32x4 acc10 = {0.f, 0.f, 0.f, 0.f}, acc11 = {0.f, 0.f, 0.f, 0.f};
#pragma unroll
  for (int kt = 0; kt < KTM; ++kt) {
    const int rb = (kt < KTG) ? BASE_G : BASE_E;
    const int rKT = (kt < KTG) ? KTG : KTE;
    const int rkt = (kt < KTG) ? kt : kt - KTG;
    bf16x8 a0h = rfrag(lds, rb, rKT, 0, rkt, lane, 0);
    bf16x8 a0l = rfrag(lds, rb, rKT, 1, rkt, lane, 0);
    bf16x8 a1h = rfrag(lds, rb, rKT, 0, rkt, lane, 1);
    bf16x8 a1l = rfrag(lds, rb, rKT, 1, rkt, lane, 1);
    const size_t wb = ((size_t)(kt * NG16 + ng0) * 64 + lane) * 8;
    bf16x8 b0h = *reinterpret_cast<const bf16x8*>(Wmh + wb);
    bf16x8 b0l = *reinterpret_cast<const bf16x8*>(Wml + wb);
    bf16x8 b1h = *reinterpret_cast<const bf16x8*>(Wmh + wb + 512);
    bf16x8 b1l = *reinterpret_cast<const bf16x8*>(Wml + wb + 512);
    acc00 = mfma3(a0h, a0l, b0h, b0l, acc00);
    acc01 = mfma3(a0h, a0l, b1h, b1l, acc01);
    acc10 = mfma3(a1h, a1l, b0h, b0l, acc10);
    acc11 = mfma3(a1h, a1l, b1h, b1l, acc11);
  }
#pragma unroll
  for (int ms = 0; ms < 2; ++ms) {
    const f32x4 aN0 = ms ? acc10 : acc00;
    const f32x4 aN1 = ms ? acc11 : acc01;
#pragma unroll
    for (int reg = 0; reg < 4; ++reg) {
      const int row = ms * 16 + (lane >> 4) * 4 + reg;
      const int grow = row0 + row;
      const float dg = (grow < M) ? deg[grow] : 1.f;
      const float sc = 1.f / fmaxf(dg, 1.f);
      const float en = dg > 0.f ? 1.f : 0.f;
#pragma unroll
      for (int ns = 0; ns < 2; ++ns) {
        const int col = (ng0 + ns) * 16 + colL;
        const float v = ns ? aN1[reg] : aN0[reg];
        const float y = (col < DOUT) ? v * sc + bm[col] * en : 0.f;
        wpack1(lds, BASE_NM, KTNM, row, col, y);
      }
    }
  }
  __syncthreads();

  // ---- phase 3: apply GEMM (H|NM) -> relu -> hnext ----
  acc00 = (f32x4){0.f, 0.f, 0.f, 0.f}; acc01 = (f32x4){0.f, 0.f, 0.f, 0.f};
  acc10 = (f32x4){0.f, 0.f, 0.f, 0.f}; acc11 = (f32x4){0.f, 0.f, 0.f, 0.f};
#pragma unroll
  for (int kt = 0; kt < KTA; ++kt) {
    const int rb = (kt < KTH) ? BASE_H : BASE_NM;
    const int rKT = (kt < KTH) ? KTH : KTNM;
    const int rkt = (kt < KTH) ? kt : kt - KTH;
    bf16x8 a0h = rfrag(lds, rb, rKT, 0, rkt, lane, 0);
    bf16x8 a0l = rfrag(lds, rb, rKT, 1, rkt, lane, 0);
    bf16x8 a1h = rfrag(lds, rb, rKT, 0, rkt, lane, 1);
    bf16x8 a1l = rfrag(lds, rb, rKT, 1, rkt, lane, 1);
    const size_t wb = ((size_t)(kt * NG16 + ng0) * 64 + lane) * 8;
    bf16x8 b0h = *reinterpret_cast<const bf16x8*>(Wah + wb);
    bf16x8 b0l = *reinterpret_cast<const bf16x8*>(Wal + wb);
    bf16x8 b1h = *reinterpret_cast<const bf16x8*>(Wah + wb + 512);
    bf16x8 b1l = *reinterpret_cast<const bf16x8*>(Wal + wb + 512);
    acc00 = mfma3(a0h, a0l, b0h, b0l, acc00);
    acc01 = mfma3(a0h, a0l, b1h, b1l, acc01);
    acc10 = mfma3(a1h, a1l, b0h, b0l, acc10);
    acc11 = mfma3(a1h, a1l, b1h, b1l, acc11);
  }
#pragma unroll
  for (int ms = 0; ms < 2; ++ms) {
    const f32x4 aN0 = ms ? acc10 : acc00;
    const f32x4 aN1 = ms ? acc11 : acc01;
#pragma unroll
    for (int reg = 0; reg < 4; ++reg) {
      const int row = ms * 16 + (lane >> 4) * 4 + reg;
      const int grow = row0 + row;
      if (grow >= M) continue;
#pragma unroll
      for (int ns = 0; ns < 2; ++ns) {
        const int col = (ng0 + ns) * 16 + colL;
        if (col < DOUT) {
          const float v = ns ? aN1[reg] : aN0[reg];
          hnext[(size_t)grow * DOUT + col] = fmaxf(v + ba[col], 0.f);
        }
      }
    }
  }
}

// ---------------- edge predictor GEMM: hsd = h3 @ [Wp_src|Wp_dst] ----------------
__global__ __launch_bounds__(64) void k_pred(const float* __restrict__ h3,
                                             const ushort* __restrict__ Wh,
                                             const ushort* __restrict__ Wl,
                                             float* __restrict__ hsd, int M) {
  const int lane = threadIdx.x;
  const int row0 = blockIdx.x * 32;
  const int rA = lane & 15;
  const int kl = (lane >> 4) * 8;
  const int r0 = (row0 + rA < M) ? row0 + rA : M - 1;
  const int r1 = (row0 + 16 + rA < M) ? row0 + 16 + rA : M - 1;
  f32x4 acc00 = {0.f, 0.f, 0.f, 0.f}, acc01 = {0.f, 0.f, 0.f, 0.f};
  f32x4 acc10 = {0.f, 0.f, 0.f, 0.f}, acc11 = {0.f, 0.f, 0.f, 0.f};
#pragma unroll
  for (int kt = 0; kt < 4; ++kt) {
    float v0[8], v1[8];
    {
      float4 x0 = *reinterpret_cast<const float4*>(h3 + (size_t)r0 * 128 + kt * 32 + kl);
      float4 x1 = *reinterpret_cast<const float4*>(h3 + (size_t)r0 * 128 + kt * 32 + kl + 4);
      v0[0]=x0.x; v0[1]=x0.y; v0[2]=x0.z; v0[3]=x0.w; v0[4]=x1.x; v0[5]=x1.y; v0[6]=x1.z; v0[7]=x1.w;
      float4 y0 = *reinterpret_cast<const float4*>(h3 + (size_t)r1 * 128 + kt * 32 + kl);
      float4 y1 = *reinterpret_cast<const float4*>(h3 + (size_t)r1 * 128 + kt * 32 + kl + 4);
      v1[0]=y0.x; v1[1]=y0.y; v1[2]=y0.z; v1[3]=y0.w; v1[4]=y1.x; v1[5]=y1.y; v1[6]=y1.z; v1[7]=y1.w;
    }
    bf16x8 a0h, a0l, a1h, a1l;
#pragma unroll
    for (int j = 0; j < 8; ++j) {
      ushort h = f2bf(v0[j]); a0h[j] = (short)h; a0l[j] = (short)f2bf(v0[j] - bf2f(h));
      ushort g = f2bf(v1[j]); a1h[j] = (short)g; a1l[j] = (short)f2bf(v1[j] - bf2f(g));
    }
    const size_t wb = ((size_t)(kt * 2) * 64 + lane) * 8;
    bf16x8 b0h = *reinterpret_cast<const bf16x8*>(Wh + wb);
    bf16x8 b0l = *reinterpret_cast<const bf16x8*>(Wl + wb);
    bf16x8 b1h = *reinterpret_cast<const bf16x8*>(Wh + wb + 512);
    bf16x8 b1l = *reinterpret_cast<const bf16x8*>(Wl + wb + 512);
    acc00 = mfma3(a0h, a0l, b0h, b0l, acc00);
    acc01 = mfma3(a0h, a0l, b1h, b1l, acc01);
    acc10 = mfma3(a1h, a1l, b0h, b0l, acc10);
    acc11 = mfma3(a1h, a1l, b1h, b1l, acc11);
  }
  const int colL = lane & 15;
#pragma unroll
  for (int ms = 0; ms < 2; ++ms) {
    const f32x4 aN0 = ms ? acc10 : acc00;
    const f32x4 aN1 = ms ? acc11 : acc01;
#pragma unroll
    for (int reg = 0; reg < 4; ++reg) {
      const int row = row0 + ms * 16 + (lane >> 4) * 4 + reg;
      if (row >= M) continue;
#pragma unroll
      for (int ns = 0; ns < 2; ++ns) {
        const int col = ns * 16 + colL;
        hsd[(size_t)row * 32 + col] = ns ? aN1[reg] : aN0[reg];
      }
    }
  }
}

// ---------------- edge output ----------------
__global__ __launch_bounds__(256) void k_edge_out(const int* __restrict__ src,
                                                  const int* __restrict__ dst,
                                                  const float* __restrict__ hsd,
                                                  const float* __restrict__ bp,
                                                  float* __restrict__ out, int E) {
  int i = blockIdx.x * 256 + threadIdx.x;
  if (i >= E * 15) return;
  int e = i / 15, c = i - e * 15;
  out[i] = hsd[(size_t)src[e] * 32 + c] + hsd[(size_t)dst[e] * 32 + 15 + c] + bp[c];
}

extern "C" void kernel_launch(void* const* d_in, const int* in_sizes, int n_in,
                              void* d_out, int out_size, void* d_ws, size_t ws_size,
                              hipStream_t stream) {
  const int N = 10000, E = 320000;
  const float* nfeats = (const float*)d_in[0];
  const float* efeats = (const float*)d_in[1];
  const int* src = (const int*)d_in[2];
  const int* dst = (const int*)d_in[3];
  const float* Wm1 = (const float*)d_in[4];
  const float* bm1 = (const float*)d_in[5];
  const float* Wa1 = (const float*)d_in[6];
  const float* ba1 = (const float*)d_in[7];
  const float* Wm2 = (const float*)d_in[8];
  const float* bm2 = (const float*)d_in[9];
  const float* Wa2 = (const float*)d_in[10];
  const float* ba2 = (const float*)d_in[11];
  const float* Wm3 = (const float*)d_in[12];
  const float* bm3 = (const float*)d_in[13];
  const float* Wa3 = (const float*)d_in[14];
  const float* ba3 = (const float*)d_in[15];
  const float* Wp = (const float*)d_in[16];
  const float* bp = (const float*)d_in[17];
  float* out = (float*)d_out;

  char* base = (char*)d_ws;
  size_t woff = 0;
  auto alloc = [&](size_t bytes) -> void* {
    void* p = base + woff;
    woff += (bytes + 255) & ~(size_t)255;
    return p;
  };
  int* cnt = (int*)alloc((size_t)N * 4);
  int* fill = (int*)alloc((size_t)N * 4);
  int* offs = (int*)alloc((size_t)(N + 1) * 4);
  int* csr_edge = (int*)alloc((size_t)E * 4);
  int* csr_src = (int*)alloc((size_t)E * 4);
  float* deg = (float*)alloc((size_t)N * 4);
  float* eagg = (float*)alloc((size_t)N * 128 * 4);
  float* h1 = (float*)alloc((size_t)N * 152 * 4);
  float* h2 = (float*)alloc((size_t)N * 152 * 4);
  float* h3 = (float*)alloc((size_t)N * 128 * 4);
  float* hsd = (float*)alloc((size_t)N * 32 * 4);
  auto wpk = [&](int kt, int ng) { return (ushort*)alloc((size_t)kt * ng * 512 * 2); };
  ushort* Wm1h = wpk(8, 10);  ushort* Wm1l = wpk(8, 10);
  ushort* Wa1h = wpk(9, 10);  ushort* Wa1l = wpk(9, 10);
  ushort* Wm2h = wpk(9, 10);  ushort* Wm2l = wpk(9, 10);
  ushort* Wa2h = wpk(10, 10); ushort* Wa2l = wpk(10, 10);
  ushort* Wm3h = wpk(9, 8);   ushort* Wm3l = wpk(9, 8);
  ushort* Wa3h = wpk(9, 8);   ushort* Wa3l = wpk(9, 8);
  ushort* Wph = wpk(4, 2);    ushort* Wpl = wpk(4, 2);

  hipMemsetAsync(cnt, 0, (size_t)N * 4, stream);
  hipMemsetAsync(fill, 0, (size_t)N * 4, stream);

  // CSR build
  k_hist<<<cdiv(E, 256), 256, 0, stream>>>(dst, cnt, E);
  k_scan<<<1, 1024, 0, stream>>>(cnt, offs, N);
  k_scatter<<<cdiv(E, 256), 256, 0, stream>>>(src, dst, offs, fill, csr_edge, csr_src, E);

  // weight packs (one fused launch)  W, hi, lo, dout, KA, KApad, KB, Korig, NG16, KT, pred
  WDescs wd;
  wd.d[0] = {Wm1, Wm1h, Wm1l, 152, 128, 128, 128, 256, 10, 8, 0};
  wd.d[1] = {Wa1, Wa1h, Wa1l, 152, 128, 128, 152, 280, 10, 9, 0};
  wd.d[2] = {Wm2, Wm2h, Wm2l, 152, 152, 160, 128, 280, 10, 9, 0};
  wd.d[3] = {Wa2, Wa2h, Wa2l, 152, 152, 160, 152, 304, 10, 10, 0};
  wd.d[4] = {Wm3, Wm3h, Wm3l, 128, 152, 160, 128, 280, 8, 9, 0};
  wd.d[5] = {Wa3, Wa3h, Wa3l, 128, 152, 160, 128, 280, 8, 9, 0};
  wd.d[6] = {Wp, Wph, Wpl, 32, 128, 128, 0, 256, 2, 4, 1};
  k_prep_W<<<dim3(cdiv(10 * 10 * 64, 256), 7), 256, 0, stream>>>(wd);

  // layer-independent edge-feature aggregation
  k_eagg<<<N, 64, 0, stream>>>(efeats, csr_edge, offs, eagg, deg);

  const int MT = cdiv(N, 32);  // 313

  // fused layers: <KTH, KTNM, NW, HW, DOUT>
  k_layer<4, 5, 5, 128, 152><<<MT, 5 * 64, 0, stream>>>(
      nfeats, eagg, deg, csr_src, offs, Wm1h, Wm1l, bm1, Wa1h, Wa1l, ba1, h1, N);
  k_layer<5, 5, 5, 152, 152><<<MT, 5 * 64, 0, stream>>>(
      h1, eagg, deg, csr_src, offs, Wm2h, Wm2l, bm2, Wa2h, Wa2l, ba2, h2, N);
  k_layer<5, 4, 4, 152, 128><<<MT, 4 * 64, 0, stream>>>(
      h2, eagg, deg, csr_src, offs, Wm3h, Wm3l, bm3, Wa3h, Wa3l, ba3, h3, N);

  // edge predictor
  k_pred<<<MT, 64, 0, stream>>>(h3, Wph, Wpl, hsd, N);
  k_edge_out<<<cdiv(E * 15, 256), 256, 0, stream>>>(src, dst, hsd, bp, out, E);
}

// Round 5
// 259.636 us; speedup vs baseline: 1.6074x; 1.6074x over previous
//
#include <hip/hip_runtime.h>
#include <hip/hip_bf16.h>
#include <cstdint>

// GraphSAGE 3-layer + edge predictor.
// Key identities:
//   segsum(concat(h[src],e)@Wm.T+bm, dst) = segsum(ph[src]) + eagg@Wme.T + deg*bm
//     where ph = h@Wmh.T  (GEMM commutes past segment-sum)
//   eagg = segsum(e), deg: layer-independent (computed once).
// ph stored bf16-hi only -> gather table 3.2MB fits per-XCD L2, half traffic.
// All other tensors bf16 hi/lo planes; GEMMs = MFMA 16x16x32 with 3-MFMA
// hi/lo split (err ~2^-17). A and W packed with the SAME (lane,elem)->k map.

static inline int cdiv(int a, int b) { return (a + b - 1) / b; }

typedef __attribute__((ext_vector_type(8))) short bf16x8;
typedef __attribute__((ext_vector_type(4))) float f32x4;

__device__ __forceinline__ ushort f2bf(float x) {
  union { float f; unsigned u; } c; c.f = x;
  unsigned r = c.u + 0x7FFFu + ((c.u >> 16) & 1u);
  return (ushort)(r >> 16);
}
__device__ __forceinline__ float bf2f(unsigned h) {
  union { unsigned u; float f; } c; c.u = h << 16;
  return c.f;
}

__device__ __forceinline__ f32x4 mfma3(bf16x8 ah, bf16x8 al, bf16x8 bh, bf16x8 bl,
                                       f32x4 acc) {
  acc = __builtin_amdgcn_mfma_f32_16x16x32_bf16(ah, bh, acc, 0, 0, 0);
  acc = __builtin_amdgcn_mfma_f32_16x16x32_bf16(al, bh, acc, 0, 0, 0);
  acc = __builtin_amdgcn_mfma_f32_16x16x32_bf16(ah, bl, acc, 0, 0, 0);
  return acc;
}

// ---------------- CSR build ----------------
__global__ __launch_bounds__(256) void k_hist(const int* __restrict__ dst,
                                              int* __restrict__ cnt, int E) {
  int e = blockIdx.x * 256 + threadIdx.x;
  if (e < E) atomicAdd(&cnt[dst[e]], 1);
}

__global__ __launch_bounds__(1024) void k_scan(const int* __restrict__ cnt,
                                               int* __restrict__ offs, int n) {
  __shared__ int smem[1024];
  const int t = threadIdx.x;
  const int base = t * 10;
  int c[10];
  int s = 0;
#pragma unroll
  for (int i = 0; i < 10; ++i) {
    int idx = base + i;
    int v = (idx < n) ? cnt[idx] : 0;
    s += v;
    c[i] = s;
  }
  smem[t] = s;
  __syncthreads();
  for (int ofs = 1; ofs < 1024; ofs <<= 1) {
    int add = (t >= ofs) ? smem[t - ofs] : 0;
    __syncthreads();
    smem[t] += add;
    __syncthreads();
  }
  int excl = smem[t] - s;
  if (t == 0) offs[0] = 0;
#pragma unroll
  for (int i = 0; i < 10; ++i) {
    int idx = base + i;
    if (idx < n) offs[idx + 1] = excl + c[i];
  }
}

__global__ __launch_bounds__(256) void k_scatter(const int* __restrict__ src,
                                                 const int* __restrict__ dst,
                                                 const int* __restrict__ offs,
                                                 int* __restrict__ fill,
                                                 int* __restrict__ csr_edge,
                                                 int* __restrict__ csr_src, int E) {
  int e = blockIdx.x * 256 + threadIdx.x;
  if (e < E) {
    int d = dst[e];
    int pos = offs[d] + atomicAdd(&fill[d], 1);
    csr_edge[pos] = e;
    csr_src[pos] = src[e];
  }
}

// ---------------- weight prep: fp32 W[dout][Korig] -> packed bf16 frag planes --
struct WDesc {
  const float* W; ushort* hi; ushort* lo;
  int dout, KA, KApad, KB, Korig, NG16, KT, pred;
};
struct WDescs { WDesc d[7]; };

__global__ __launch_bounds__(256) void k_prep_W(WDescs P) {
  const WDesc d = P.d[blockIdx.y];
  int tid = blockIdx.x * 256 + threadIdx.x;
  if (tid >= d.KT * d.NG16 * 64) return;
  int lane = tid & 63;
  int g = (tid >> 6) % d.NG16;
  int t = (tid >> 6) / d.NG16;
  int col = g * 16 + (lane & 15);
  int kbase = t * 32 + ((lane >> 4) * 8);
  size_t o = (size_t)tid * 8;
#pragma unroll
  for (int j = 0; j < 8; ++j) {
    int kk = kbase + j;
    float w = 0.f;
    if (!d.pred) {
      if (col < d.dout) {
        if (kk < d.KApad) {
          if (kk < d.KA) w = d.W[(size_t)col * d.Korig + kk];
        } else {
          int kb = kk - d.KApad;
          if (kb < d.KB) w = d.W[(size_t)col * d.Korig + d.KA + kb];
        }
      }
    } else {
      if (col < 15) w = d.W[(size_t)col * 256 + kk];
      else if (col < 30) w = d.W[(size_t)(col - 15) * 256 + 128 + kk];
    }
    ushort h = f2bf(w);
    d.hi[o + j] = h;
    d.lo[o + j] = f2bf(w - bf2f(h));
  }
}

// ---------------- nfeats fp32 -> hi/lo planes ----------------
__global__ __launch_bounds__(256) void k_prep_nf(const float* __restrict__ x,
                                                 ushort* __restrict__ hi,
                                                 ushort* __restrict__ lo, int n) {
  int i = blockIdx.x * 256 + threadIdx.x;
  if (i >= n) return;
  float v = x[i];
  ushort h = f2bf(v);
  hi[i] = h;
  lo[i] = f2bf(v - bf2f(h));
}

// ---------------- edge-feature aggregation (the big HBM read) ----------------
__global__ __launch_bounds__(64) void k_eagg(const float* __restrict__ efeats,
                                             const int* __restrict__ csr_edge,
                                             const int* __restrict__ offs,
                                             ushort* __restrict__ ehi,
                                             ushort* __restrict__ elo,
                                             float* __restrict__ deg) {
  int d = blockIdx.x, lane = threadIdx.x;
  int s = offs[d], t = offs[d + 1];
  float2 a0 = make_float2(0.f, 0.f), a1 = a0, a2 = a0, a3 = a0;
  int j = s;
  for (; j + 3 < t; j += 4) {
    int e0 = csr_edge[j], e1 = csr_edge[j + 1];
    int e2 = csr_edge[j + 2], e3 = csr_edge[j + 3];
    float2 v0 = *reinterpret_cast<const float2*>(efeats + (size_t)e0 * 128 + lane * 2);
    float2 v1 = *reinterpret_cast<const float2*>(efeats + (size_t)e1 * 128 + lane * 2);
    float2 v2 = *reinterpret_cast<const float2*>(efeats + (size_t)e2 * 128 + lane * 2);
    float2 v3 = *reinterpret_cast<const float2*>(efeats + (size_t)e3 * 128 + lane * 2);
    a0.x += v0.x; a0.y += v0.y;
    a1.x += v1.x; a1.y += v1.y;
    a2.x += v2.x; a2.y += v2.y;
    a3.x += v3.x; a3.y += v3.y;
  }
  for (; j < t; ++j) {
    int e0 = csr_edge[j];
    float2 v0 = *reinterpret_cast<const float2*>(efeats + (size_t)e0 * 128 + lane * 2);
    a0.x += v0.x; a0.y += v0.y;
  }
  float sx = (a0.x + a1.x) + (a2.x + a3.x);
  float sy = (a0.y + a1.y) + (a2.y + a3.y);
  size_t o = (size_t)d * 128 + lane * 2;
  ushort hx = f2bf(sx), hy = f2bf(sy);
  ehi[o] = hx; ehi[o + 1] = hy;
  elo[o] = f2bf(sx - bf2f(hx)); elo[o + 1] = f2bf(sy - bf2f(hy));
  if (lane == 0) deg[d] = (float)(t - s);
}

// ---------------- generic MFMA GEMM over bf16 hi/lo planes ----------------
// Y[M][*] = post( concat(Aplanes[SA=KTA*32], Bplanes[SB=KTB*32]) @ W )
// 1 wave/block, 32x32 tile. MODE 0: proj -> Yhi only (y=acc, 0 for pad cols)
// MODE 1: apply -> relu(acc+bias) -> Yhi/Ylo (0 for pad cols)
// MODE 2: plain fp32 -> Yf
template <int KTA, int KTB, int MODE>
__global__ __launch_bounds__(64) void k_mfma(
    const ushort* __restrict__ Ahi, const ushort* __restrict__ Alo,
    const ushort* __restrict__ Bhi, const ushort* __restrict__ Blo,
    const ushort* __restrict__ Whi, const ushort* __restrict__ Wlo,
    const float* __restrict__ bias,
    ushort* __restrict__ Yhi, ushort* __restrict__ Ylo, float* __restrict__ Yf,
    int dout_real, int NG16, int OSTR, int M) {
  constexpr int KT = KTA + KTB;
  constexpr int SA = KTA * 32;
  constexpr int SB = (KTB > 0 ? KTB : 1) * 32;
  const int lane = threadIdx.x;
  const int ng0 = blockIdx.x * 2;
  const int row0 = blockIdx.y * 32;
  const int rA = lane & 15;
  const int kl = (lane >> 4) * 8;
  const int r0 = (row0 + rA < M) ? row0 + rA : M - 1;
  const int r1 = (row0 + 16 + rA < M) ? row0 + 16 + rA : M - 1;
  f32x4 acc00 = {0.f, 0.f, 0.f, 0.f}, acc01 = {0.f, 0.f, 0.f, 0.f};
  f32x4 acc10 = {0.f, 0.f, 0.f, 0.f}, acc11 = {0.f, 0.f, 0.f, 0.f};
#pragma unroll
  for (int kt = 0; kt < KT; ++kt) {
    bf16x8 a0h, a0l, a1h, a1l;
    if (KTB == 0 || kt < KTA) {
      const size_t o0 = (size_t)r0 * SA + kt * 32 + kl;
      const size_t o1 = (size_t)r1 * SA + kt * 32 + kl;
      a0h = *reinterpret_cast<const bf16x8*>(Ahi + o0);
      a0l = *reinterpret_cast<const bf16x8*>(Alo + o0);
      a1h = *reinterpret_cast<const bf16x8*>(Ahi + o1);
      a1l = *reinterpret_cast<const bf16x8*>(Alo + o1);
    } else {
      const int kb = (kt - KTA) * 32 + kl;
      const size_t o0 = (size_t)r0 * SB + kb;
      const size_t o1 = (size_t)r1 * SB + kb;
      a0h = *reinterpret_cast<const bf16x8*>(Bhi + o0);
      a0l = *reinterpret_cast<const bf16x8*>(Blo + o0);
      a1h = *reinterpret_cast<const bf16x8*>(Bhi + o1);
      a1l = *reinterpret_cast<const bf16x8*>(Blo + o1);
    }
    const size_t wb = ((size_t)(kt * NG16 + ng0) * 64 + lane) * 8;
    bf16x8 b0h = *reinterpret_cast<const bf16x8*>(Whi + wb);
    bf16x8 b0l = *reinterpret_cast<const bf16x8*>(Wlo + wb);
    bf16x8 b1h = *reinterpret_cast<const bf16x8*>(Whi + wb + 512);
    bf16x8 b1l = *reinterpret_cast<const bf16x8*>(Wlo + wb + 512);
    acc00 = mfma3(a0h, a0l, b0h, b0l, acc00);
    acc01 = mfma3(a0h, a0l, b1h, b1l, acc01);
    acc10 = mfma3(a1h, a1l, b0h, b0l, acc10);
    acc11 = mfma3(a1h, a1l, b1h, b1l, acc11);
  }
  // C/D layout: col = lane&15, row = (lane>>4)*4 + reg  [m89-verified]
  const int colL = lane & 15;
#pragma unroll
  for (int ms = 0; ms < 2; ++ms) {
    const f32x4 aN0 = ms ? acc10 : acc00;
    const f32x4 aN1 = ms ? acc11 : acc01;
#pragma unroll
    for (int reg = 0; reg < 4; ++reg) {
      const int row = row0 + ms * 16 + (lane >> 4) * 4 + reg;
      if (row >= M) continue;
#pragma unroll
      for (int ns = 0; ns < 2; ++ns) {
        const int col = (ng0 + ns) * 16 + colL;
        const float v = ns ? aN1[reg] : aN0[reg];
        if constexpr (MODE == 2) {
          Yf[(size_t)row * OSTR + col] = v;
        } else if constexpr (MODE == 0) {
          const float y = (col < dout_real) ? v : 0.f;
          Yhi[(size_t)row * OSTR + col] = f2bf(y);
        } else {
          const float y = (col < dout_real) ? fmaxf(v + bias[col], 0.f) : 0.f;
          ushort h = f2bf(y);
          Yhi[(size_t)row * OSTR + col] = h;
          Ylo[(size_t)row * OSTR + col] = f2bf(y - bf2f(h));
        }
      }
    }
  }
}

// ---------------- batched pe GEMM: pe_l = eagg@Wme_l.T + deg*bm_l ----------------
struct PeD { const ushort* Wh; const ushort* Wl; const float* bm; float* pe;
             int NG16, WPAD, dout; };
struct PeDs { PeD d[3]; };

__global__ __launch_bounds__(64) void k_pe(PeDs P,
                                           const ushort* __restrict__ Ehi,
                                           const ushort* __restrict__ Elo,
                                           const float* __restrict__ deg, int M) {
  const PeD d = P.d[blockIdx.z];
  const int ng0 = blockIdx.x * 2;
  if (ng0 >= d.NG16) return;
  const int lane = threadIdx.x;
  const int row0 = blockIdx.y * 32;
  const int rA = lane & 15;
  const int kl = (lane >> 4) * 8;
  const int r0 = (row0 + rA < M) ? row0 + rA : M - 1;
  const int r1 = (row0 + 16 + rA < M) ? row0 + 16 + rA : M - 1;
  f32x4 acc00 = {0.f, 0.f, 0.f, 0.f}, acc01 = {0.f, 0.f, 0.f, 0.f};
  f32x4 acc10 = {0.f, 0.f, 0.f, 0.f}, acc11 = {0.f, 0.f, 0.f, 0.f};
#pragma unroll
  for (int kt = 0; kt < 4; ++kt) {
    const size_t o0 = (size_t)r0 * 128 + kt * 32 + kl;
    const size_t o1 = (size_t)r1 * 128 + kt * 32 + kl;
    bf16x8 a0h = *reinterpret_cast<const bf16x8*>(Ehi + o0);
    bf16x8 a0l = *reinterpret_cast<const bf16x8*>(Elo + o0);
    bf16x8 a1h = *reinterpret_cast<const bf16x8*>(Ehi + o1);
    bf16x8 a1l = *reinterpret_cast<const bf16x8*>(Elo + o1);
    const size_t wb = ((size_t)(kt * d.NG16 + ng0) * 64 + lane) * 8;
    bf16x8 b0h = *reinterpret_cast<const bf16x8*>(d.Wh + wb);
    bf16x8 b0l = *reinterpret_cast<const bf16x8*>(d.Wl + wb);
    bf16x8 b1h = *reinterpret_cast<const bf16x8*>(d.Wh + wb + 512);
    bf16x8 b1l = *reinterpret_cast<const bf16x8*>(d.Wl + wb + 512);
    acc00 = mfma3(a0h, a0l, b0h, b0l, acc00);
    acc01 = mfma3(a0h, a0l, b1h, b1l, acc01);
    acc10 = mfma3(a1h, a1l, b0h, b0l, acc10);
    acc11 = mfma3(a1h, a1l, b1h, b1l, acc11);
  }
  const int colL = lane & 15;
#pragma unroll
  for (int ms = 0; ms < 2; ++ms) {
    const f32x4 aN0 = ms ? acc10 : acc00;
    const f32x4 aN1 = ms ? acc11 : acc01;
#pragma unroll
    for (int reg = 0; reg < 4; ++reg) {
      const int row = row0 + ms * 16 + (lane >> 4) * 4 + reg;
      if (row >= M) continue;
      const float dg = deg[row];
#pragma unroll
      for (int ns = 0; ns < 2; ++ns) {
        const int col = (ng0 + ns) * 16 + colL;
        const float v = ns ? aN1[reg] : aN0[reg];
        d.pe[(size_t)row * d.WPAD + col] = (col < d.dout) ? v + dg * d.bm[col] : 0.f;
      }
    }
  }
}

// ---------------- gather of projected table: nm = (segsum(ph[src]) + pe)/deg ----
// ph is bf16-hi only, width WP (L2-resident: N*WP*2 <= 3.2 MB).
template <int WP>
__global__ __launch_bounds__(64) void k_gath(const ushort* __restrict__ ph,
                                             const float* __restrict__ pe,
                                             const float* __restrict__ deg,
                                             const int* __restrict__ csr_src,
                                             const int* __restrict__ offs,
                                             ushort* __restrict__ nmhi,
                                             ushort* __restrict__ nmlo) {
  constexpr int PAIRS = WP / 2;
  constexpr int NV = (PAIRS + 63) / 64;
  const int d = blockIdx.x, lane = threadIdx.x;
  const int s = offs[d], t = offs[d + 1];
  float2 acc[NV][4];
#pragma unroll
  for (int v = 0; v < NV; ++v)
#pragma unroll
    for (int u = 0; u < 4; ++u) acc[v][u] = make_float2(0.f, 0.f);
  int j = s;
  for (; j + 3 < t; j += 4) {
    int s0 = csr_src[j], s1 = csr_src[j + 1];
    int s2 = csr_src[j + 2], s3 = csr_src[j + 3];
#pragma unroll
    for (int v = 0; v < NV; ++v) {
      int p = lane + 64 * v;
      if (p < PAIRS) {
        unsigned x0 = *reinterpret_cast<const unsigned*>(ph + (size_t)s0 * WP + 2 * p);
        unsigned x1 = *reinterpret_cast<const unsigned*>(ph + (size_t)s1 * WP + 2 * p);
        unsigned x2 = *reinterpret_cast<const unsigned*>(ph + (size_t)s2 * WP + 2 * p);
        unsigned x3 = *reinterpret_cast<const unsigned*>(ph + (size_t)s3 * WP + 2 * p);
        acc[v][0].x += bf2f(x0 & 0xffffu); acc[v][0].y += bf2f(x0 >> 16);
        acc[v][1].x += bf2f(x1 & 0xffffu); acc[v][1].y += bf2f(x1 >> 16);
        acc[v][2].x += bf2f(x2 & 0xffffu); acc[v][2].y += bf2f(x2 >> 16);
        acc[v][3].x += bf2f(x3 & 0xffffu); acc[v][3].y += bf2f(x3 >> 16);
      }
    }
  }
  for (; j < t; ++j) {
    int s0 = csr_src[j];
#pragma unroll
    for (int v = 0; v < NV; ++v) {
      int p = lane + 64 * v;
      if (p < PAIRS) {
        unsigned x0 = *reinterpret_cast<const unsigned*>(ph + (size_t)s0 * WP + 2 * p);
        acc[v][0].x += bf2f(x0 & 0xffffu); acc[v][0].y += bf2f(x0 >> 16);
      }
    }
  }
  const float dg = deg[d];
  const float inv = 1.f / fmaxf(dg, 1.f);
#pragma unroll
  for (int v = 0; v < NV; ++v) {
    int p = lane + 64 * v;
    if (p < PAIRS) {
      float sx = (acc[v][0].x + acc[v][1].x) + (acc[v][2].x + acc[v][3].x);
      float sy = (acc[v][0].y + acc[v][1].y) + (acc[v][2].y + acc[v][3].y);
      float2 pv = *reinterpret_cast<const float2*>(pe + (size_t)d * WP + 2 * p);
      float nx = (sx + pv.x) * inv;
      float ny = (sy + pv.y) * inv;
      size_t o = (size_t)d * WP + 2 * p;
      ushort hx = f2bf(nx), hy = f2bf(ny);
      unsigned uh = (unsigned)hx | ((unsigned)hy << 16);
      unsigned ul = (unsigned)f2bf(nx - bf2f(hx)) | ((unsigned)f2bf(ny - bf2f(hy)) << 16);
      *reinterpret_cast<unsigned*>(nmhi + o) = uh;
      *reinterpret_cast<unsigned*>(nmlo + o) = ul;
    }
  }
}

// ---------------- edge output (hsd stride 32: cols 0..14 src, 15..29 dst) ------
__global__ __launch_bounds__(256) void k_edge_out(const int* __restrict__ src,
                                                  const int* __restrict__ dst,
                                                  const float* __restrict__ hsd,
                                                  const float* __restrict__ bp,
                                                  float* __restrict__ out, int E) {
  int i = blockIdx.x * 256 + threadIdx.x;
  if (i >= E * 15) return;
  int e = i / 15, c = i - e * 15;
  out[i] = hsd[(size_t)src[e] * 32 + c] + hsd[(size_t)dst[e] * 32 + 15 + c] + bp[c];
}

extern "C" void kernel_launch(void* const* d_in, const int* in_sizes, int n_in,
                              void* d_out, int out_size, void* d_ws, size_t ws_size,
                              hipStream_t stream) {
  const int N = 10000, E = 320000;
  const float* nfeats = (const float*)d_in[0];
  const float* efeats = (const float*)d_in[1];
  const int* src = (const int*)d_in[2];
  const int* dst = (const int*)d_in[3];
  const float* Wm1 = (const float*)d_in[4];
  const float* bm1 = (const float*)d_in[5];
  const float* Wa1 = (const float*)d_in[6];
  const float* ba1 = (const float*)d_in[7];
  const float* Wm2 = (const float*)d_in[8];
  const float* bm2 = (const float*)d_in[9];
  const float* Wa2 = (const float*)d_in[10];
  const float* ba2 = (const float*)d_in[11];
  const float* Wm3 = (const float*)d_in[12];
  const float* bm3 = (const float*)d_in[13];
  const float* Wa3 = (const float*)d_in[14];
  const float* ba3 = (const float*)d_in[15];
  const float* Wp = (const float*)d_in[16];
  const float* bp = (const float*)d_in[17];
  float* out = (float*)d_out;

  char* base = (char*)d_ws;
  size_t woff = 0;
  auto alloc = [&](size_t bytes) -> void* {
    void* p = base + woff;
    woff += (bytes + 255) & ~(size_t)255;
    return p;
  };
  int* cnt = (int*)alloc((size_t)2 * N * 4);  // cnt | fill adjacent
  int* fill = cnt + N;
  int* offs = (int*)alloc((size_t)(N + 1) * 4);
  int* csr_edge = (int*)alloc((size_t)E * 4);
  int* csr_src = (int*)alloc((size_t)E * 4);
  float* deg = (float*)alloc((size_t)N * 4);
  auto aplane = [&](int w) { return (ushort*)alloc((size_t)N * w * 2); };
  ushort* nf_hi = aplane(128);  ushort* nf_lo = aplane(128);
  ushort* ea_hi = aplane(128);  ushort* ea_lo = aplane(128);
  ushort* h1_hi = aplane(160);  ushort* h1_lo = aplane(160);
  ushort* h2_hi = aplane(160);  ushort* h2_lo = aplane(160);
  ushort* h3_hi = aplane(128);  ushort* h3_lo = aplane(128);
  ushort* nm_hi = aplane(160);  ushort* nm_lo = aplane(160);
  ushort* ph = aplane(160);  // bf16-hi projected table (reused per layer)
  float* pe1 = (float*)alloc((size_t)N * 160 * 4);
  float* pe2 = (float*)alloc((size_t)N * 160 * 4);
  float* pe3 = (float*)alloc((size_t)N * 128 * 4);
  float* hsd = (float*)alloc((size_t)N * 32 * 4);
  auto wpk = [&](int kt, int ng) { return (ushort*)alloc((size_t)kt * ng * 512 * 2); };
  ushort* Wm1h = wpk(8, 10);  ushort* Wm1l = wpk(8, 10);
  ushort* Wa1h = wpk(9, 10);  ushort* Wa1l = wpk(9, 10);
  ushort* Wm2h = wpk(9, 10);  ushort* Wm2l = wpk(9, 10);
  ushort* Wa2h = wpk(10, 10); ushort* Wa2l = wpk(10, 10);
  ushort* Wm3h = wpk(9, 8);   ushort* Wm3l = wpk(9, 8);
  ushort* Wa3h = wpk(9, 8);   ushort* Wa3l = wpk(9, 8);
  ushort* Wph = wpk(4, 2);    ushort* Wpl = wpk(4, 2);

  hipMemsetAsync(cnt, 0, (size_t)2 * N * 4, stream);

  // CSR build
  k_hist<<<cdiv(E, 256), 256, 0, stream>>>(dst, cnt, E);
  k_scan<<<1, 1024, 0, stream>>>(cnt, offs, N);
  k_scatter<<<cdiv(E, 256), 256, 0, stream>>>(src, dst, offs, fill, csr_edge, csr_src, E);

  // weight packs: W, hi, lo, dout, KA, KApad, KB, Korig, NG16, KT, pred
  WDescs wd;
  wd.d[0] = {Wm1, Wm1h, Wm1l, 152, 128, 128, 128, 256, 10, 8, 0};
  wd.d[1] = {Wa1, Wa1h, Wa1l, 152, 128, 128, 152, 280, 10, 9, 0};
  wd.d[2] = {Wm2, Wm2h, Wm2l, 152, 152, 160, 128, 280, 10, 9, 0};
  wd.d[3] = {Wa2, Wa2h, Wa2l, 152, 152, 160, 152, 304, 10, 10, 0};
  wd.d[4] = {Wm3, Wm3h, Wm3l, 128, 152, 160, 128, 280, 8, 9, 0};
  wd.d[5] = {Wa3, Wa3h, Wa3l, 128, 152, 160, 128, 280, 8, 9, 0};
  wd.d[6] = {Wp, Wph, Wpl, 32, 128, 128, 0, 256, 2, 4, 1};
  k_prep_W<<<dim3(cdiv(10 * 10 * 64, 256), 7), 256, 0, stream>>>(wd);
  k_prep_nf<<<cdiv(N * 128, 256), 256, 0, stream>>>(nfeats, nf_hi, nf_lo, N * 128);

  // eagg + deg (164 MB HBM stream)
  k_eagg<<<N, 64, 0, stream>>>(efeats, csr_edge, offs, ea_hi, ea_lo, deg);

  // batched pe_l = eagg@Wme_l.T + deg*bm_l   (W pre-offset to e-part tiles)
  PeDs pd;
  pd.d[0] = {Wm1h + (size_t)4 * 10 * 512, Wm1l + (size_t)4 * 10 * 512, bm1, pe1, 10, 160, 152};
  pd.d[1] = {Wm2h + (size_t)5 * 10 * 512, Wm2l + (size_t)5 * 10 * 512, bm2, pe2, 10, 160, 152};
  pd.d[2] = {Wm3h + (size_t)5 * 8 * 512,  Wm3l + (size_t)5 * 8 * 512,  bm3, pe3, 8, 128, 128};
  const int MT = cdiv(N, 32);  // 313
  k_pe<<<dim3(5, MT, 3), 64, 0, stream>>>(pd, ea_hi, ea_lo, deg, N);

  // layer 1: proj(nf@Wm1h) -> gather -> apply
  k_mfma<4, 0, 0><<<dim3(5, MT), 64, 0, stream>>>(
      nf_hi, nf_lo, nullptr, nullptr, Wm1h, Wm1l, nullptr, ph, nullptr, nullptr, 152, 10, 160, N);
  k_gath<160><<<N, 64, 0, stream>>>(ph, pe1, deg, csr_src, offs, nm_hi, nm_lo);
  k_mfma<4, 5, 1><<<dim3(5, MT), 64, 0, stream>>>(
      nf_hi, nf_lo, nm_hi, nm_lo, Wa1h, Wa1l, ba1, h1_hi, h1_lo, nullptr, 152, 10, 160, N);
  // layer 2
  k_mfma<5, 0, 0><<<dim3(5, MT), 64, 0, stream>>>(
      h1_hi, h1_lo, nullptr, nullptr, Wm2h, Wm2l, nullptr, ph, nullptr, nullptr, 152, 10, 160, N);
  k_gath<160><<<N, 64, 0, stream>>>(ph, pe2, deg, csr_src, offs, nm_hi, nm_lo);
  k_mfma<5, 5, 1><<<dim3(5, MT), 64, 0, stream>>>(
      h1_hi, h1_lo, nm_hi, nm_lo, Wa2h, Wa2l, ba2, h2_hi, h2_lo, nullptr, 152, 10, 160, N);
  // layer 3 (dout 128)
  k_mfma<5, 0, 0><<<dim3(4, MT), 64, 0, stream>>>(
      h2_hi, h2_lo, nullptr, nullptr, Wm3h, Wm3l, nullptr, ph, nullptr, nullptr, 128, 8, 128, N);
  k_gath<128><<<N, 64, 0, stream>>>(ph, pe3, deg, csr_src, offs, nm_hi, nm_lo);
  k_mfma<5, 4, 1><<<dim3(4, MT), 64, 0, stream>>>(
      h2_hi, h2_lo, nm_hi, nm_lo, Wa3h, Wa3l, ba3, h3_hi, h3_lo, nullptr, 128, 8, 128, N);

  // edge predictor: hsd = h3 @ [Wp_src | Wp_dst]  (fp32, stride 32)
  k_mfma<4, 0, 2><<<dim3(1, MT), 64, 0, stream>>>(
      h3_hi, h3_lo, nullptr, nullptr, Wph, Wpl, nullptr, nullptr, nullptr, hsd, 32, 2, 32, N);
  k_edge_out<<<cdiv(E * 15, 256), 256, 0, stream>>>(src, dst, hsd, bp, out, E);
}